// Round 2
// baseline (848.076 us; speedup 1.0000x reference)
//
#include <hip/hip_runtime.h>

#define HID 32
#define MIN_WEIGHT -100000.0f

// ---------------------------------------------------------------------------
// Fill output with MIN_WEIGHT (vectorized). n is element count (multiple of 4
// not required; tail handled).
__global__ __launch_bounds__(256) void fill_kernel(float* __restrict__ out, int n, float val) {
    int i = blockIdx.x * blockDim.x + threadIdx.x;
    int stride = gridDim.x * blockDim.x;
    int n4 = n >> 2;
    float4 v4 = {val, val, val, val};
    float4* out4 = (float4*)out;
    for (int j = i; j < n4; j += stride) out4[j] = v4;
    // tail
    for (int j = n4 * 4 + i; j < n; j += stride) out[j] = val;
}

// ---------------------------------------------------------------------------
// Gathered GEMM + ReLU + projection(s), G lanes cooperate per node.
//   g   = relu(emb[n_map[sel ? sel[node] : node]] @ W)        (ROW -> 32)
//   o0  = g @ P0 ; o1 = g @ P1 (if TWO)                       (32 -> 32)
// Lane loads CHUNK=ROW/G contiguous row floats (coalesced per group),
// computes partial acc[32], butterfly-reduces across the aligned G-lane
// group, then each lane emits 32/G projection outputs (coalesced store).
template <int ROW, int G, bool TWO>
__global__ __launch_bounds__(256) void gnode_kernel(
    const float* __restrict__ emb, const int* __restrict__ n_map,
    const int* __restrict__ sel,  // optional indirection (offset_node) or null
    const float* __restrict__ W,  // ROW x 32
    const float* __restrict__ P0, const float* __restrict__ P1,  // 32 x 32
    float* __restrict__ o0, float* __restrict__ o1, int n) {
    constexpr int CHUNK = ROW / G;   // row floats per lane
    constexpr int OPL = HID / G;     // projection outputs per lane
    constexpr int NPB = 256 / G;     // nodes per block

    int node = blockIdx.x * NPB + threadIdx.x / G;
    int lane = threadIdx.x % G;
    if (node >= n) return;
    int local = sel ? sel[node] : node;
    int gn = n_map[local];

    // load my row chunk
    const float* row = emb + (size_t)gn * ROW + lane * CHUNK;
    float r[CHUNK];
#pragma unroll
    for (int j = 0; j < CHUNK; j += 4) {
        float4 v = *(const float4*)(row + j);
        r[j + 0] = v.x; r[j + 1] = v.y; r[j + 2] = v.z; r[j + 3] = v.w;
    }

    // partial layer-1 accumulation over my K chunk
    float acc[HID];
#pragma unroll
    for (int k = 0; k < HID; ++k) acc[k] = 0.f;
#pragma unroll
    for (int j = 0; j < CHUNK; ++j) {
        float ev = r[j];
        const float4* wr = (const float4*)(W + (size_t)(lane * CHUNK + j) * HID);
#pragma unroll
        for (int q = 0; q < 8; ++q) {
            float4 w4 = wr[q];
            acc[q * 4 + 0] = fmaf(ev, w4.x, acc[q * 4 + 0]);
            acc[q * 4 + 1] = fmaf(ev, w4.y, acc[q * 4 + 1]);
            acc[q * 4 + 2] = fmaf(ev, w4.z, acc[q * 4 + 2]);
            acc[q * 4 + 3] = fmaf(ev, w4.w, acc[q * 4 + 3]);
        }
    }

    // butterfly reduce across the G-lane group (groups are G-aligned)
#pragma unroll
    for (int m = G / 2; m >= 1; m >>= 1) {
#pragma unroll
        for (int k = 0; k < HID; ++k) acc[k] += __shfl_xor(acc[k], m, 64);
    }
    // relu
#pragma unroll
    for (int k = 0; k < HID; ++k) acc[k] = fmaxf(acc[k], 0.f);

    // projection 0: each lane computes OPL outputs
    {
        float o[OPL];
#pragma unroll
        for (int t = 0; t < OPL; ++t) o[t] = 0.f;
#pragma unroll
        for (int j = 0; j < HID; ++j) {
            float gv = acc[j];
            const float* pr = P0 + j * HID + lane * OPL;
#pragma unroll
            for (int t = 0; t < OPL; ++t) o[t] = fmaf(gv, pr[t], o[t]);
        }
        float* dst = o0 + (size_t)node * HID + lane * OPL;
#pragma unroll
        for (int t = 0; t < OPL; t += 4) {
            float4 v = {o[t], o[t + 1], o[t + 2], o[t + 3]};
            *(float4*)(dst + t) = v;
        }
    }
    if (TWO) {
        float o[OPL];
#pragma unroll
        for (int t = 0; t < OPL; ++t) o[t] = 0.f;
#pragma unroll
        for (int j = 0; j < HID; ++j) {
            float gv = acc[j];
            const float* pr = P1 + j * HID + lane * OPL;
#pragma unroll
            for (int t = 0; t < OPL; ++t) o[t] = fmaf(gv, pr[t], o[t]);
        }
        float* dst = o1 + (size_t)node * HID + lane * OPL;
#pragma unroll
        for (int t = 0; t < OPL; t += 4) {
            float4 v = {o[t], o[t + 1], o[t + 2], o[t + 3]};
            *(float4*)(dst + t) = v;
        }
    }
}

// ---------------------------------------------------------------------------
// Per-edge: att = relu(SA[src] + DB[dst] + t2[batch] + be1) @ We2 + be2
__global__ __launch_bounds__(256) void edge_kernel(
    const int* __restrict__ hop_idx, int n_e, const int* __restrict__ src,
    const int* __restrict__ dst, const int* __restrict__ e_batch,
    const float* __restrict__ SA, const float* __restrict__ DB,
    const float* __restrict__ t2, const float* __restrict__ be1,
    const float* __restrict__ We2, const float* __restrict__ be2,
    float* __restrict__ out) {
    int i = blockIdx.x * blockDim.x + threadIdx.x;
    if (i >= n_e) return;
    int e = hop_idx[i];
    const float* sv = SA + (size_t)src[e] * HID;
    const float* dv = DB + (size_t)dst[e] * HID;
    const float* tv = t2 + (size_t)e_batch[e] * HID;
    float att = be2[0];
#pragma unroll
    for (int k = 0; k < HID; k += 4) {
        float4 s4 = *(const float4*)(sv + k);
        float4 d4 = *(const float4*)(dv + k);
        float4 t4 = *(const float4*)(tv + k);
        float h;
        h = fmaxf(s4.x + d4.x + t4.x + be1[k + 0], 0.f); att = fmaf(h, We2[k + 0], att);
        h = fmaxf(s4.y + d4.y + t4.y + be1[k + 1], 0.f); att = fmaf(h, We2[k + 1], att);
        h = fmaxf(s4.z + d4.z + t4.z + be1[k + 2], 0.f); att = fmaf(h, We2[k + 2], att);
        h = fmaxf(s4.w + d4.w + t4.w + be1[k + 3], 0.f); att = fmaf(h, We2[k + 3], att);
    }
    out[e] = att;
}

// ---------------------------------------------------------------------------
extern "C" void kernel_launch(void* const* d_in, const int* in_sizes, int n_in,
                              void* d_out, int out_size, void* d_ws, size_t ws_size,
                              hipStream_t stream) {
    const float* emb0 = (const float*)d_in[0];
    const float* emb1 = (const float*)d_in[1];
    const float* emb2 = (const float*)d_in[2];
    const int* n_map = (const int*)d_in[3];
    const int* src = (const int*)d_in[4];
    const int* dst = (const int*)d_in[5];
    const int* e_batch = (const int*)d_in[6];
    const int* offset_node = (const int*)d_in[7];
    const int* one_hop = (const int*)d_in[8];
    const int* two_hop = (const int*)d_in[9];
    const float* W0 = (const float*)d_in[10];
    const float* W1 = (const float*)d_in[11];
    const float* W2 = (const float*)d_in[12];
    const float* We1 = (const float*)d_in[13];
    const float* be1 = (const float*)d_in[14];
    const float* We2 = (const float*)d_in[15];
    const float* be2 = (const float*)d_in[16];

    const int n_nodes = in_sizes[3];
    const int E = in_sizes[4];
    const int batch = in_sizes[7];
    const int H1 = in_sizes[8];  // one-hop edge count
    const int H2 = in_sizes[9];  // two-hop edge count

    float* out = (float*)d_out;

    const float* A = We1;             // rows 0..31   (multiplies s)
    const float* B = We1 + 32 * HID;  // rows 32..63  (multiplies d)
    const float* T = We1 + 64 * HID;  // rows 64..95  (multiplies t)

    // workspace layout: a0 | a1 | b1 | b2 | t2
    float* a0 = (float*)d_ws;
    float* a1 = a0 + (size_t)n_nodes * HID;
    float* b1 = a1 + (size_t)n_nodes * HID;
    float* b2 = b1 + (size_t)n_nodes * HID;
    float* t2 = b2 + (size_t)n_nodes * HID;

    // 1) fill output with MIN_WEIGHT
    {
        int total = 2 * E;
        fill_kernel<<<2048, 256, 0, stream>>>(out, total, MIN_WEIGHT);
    }
    // 2) per-node projected features (three gathered GEMMs, G lanes/node)
    //    a0 = relu(emb0@W0)@A          (ROW=128, G=4 -> 400K threads)
    gnode_kernel<128, 4, false><<<(n_nodes + 63) / 64, 256, 0, stream>>>(
        emb0, n_map, nullptr, W0, A, nullptr, a0, nullptr, n_nodes);
    //    a1 = relu(emb1@W1)@A, b1 = ...@B   (ROW=256, G=8 -> 800K threads)
    gnode_kernel<256, 8, true><<<(n_nodes + 31) / 32, 256, 0, stream>>>(
        emb1, n_map, nullptr, W1, A, B, a1, b1, n_nodes);
    //    b2 = relu(emb2@W2)@B          (ROW=64, G=4 -> 400K threads)
    gnode_kernel<64, 4, false><<<(n_nodes + 63) / 64, 256, 0, stream>>>(
        emb2, n_map, nullptr, W2, B, nullptr, b2, nullptr, n_nodes);
    // 3) per-batch target features: t2 = relu(emb2[n_map[offset]]@W2)@T
    gnode_kernel<64, 4, false><<<(batch + 63) / 64, 256, 0, stream>>>(
        emb2, n_map, offset_node, W2, T, nullptr, t2, nullptr, batch);
    // 4) one-hop edges -> slab 1 ; src via W1@A (a1) + dst via W2@B (b2)
    edge_kernel<<<(H1 + 255) / 256, 256, 0, stream>>>(
        one_hop, H1, src, dst, e_batch, a1, b2, t2, be1, We2, be2, out + (size_t)E);
    // 5) two-hop edges -> slab 0 ; src via W0@A (a0) + dst via W1@B (b1)
    edge_kernel<<<(H2 + 255) / 256, 256, 0, stream>>>(
        two_hop, H2, src, dst, e_batch, a0, b1, t2, be1, We2, be2, out);
}

// Round 3
// 226.467 us; speedup vs baseline: 3.7448x; 3.7448x over previous
//
#include <hip/hip_runtime.h>

#define HID 32
#define MIN_WEIGHT -100000.0f

// ---------------------------------------------------------------------------
// Node-stage kernel.  Block = 256 threads = 64 nodes x 4 octs.
//   lane (threadIdx&63)  = node within block   (gather loads per-lane)
//   oct  (threadIdx>>6)  = which 8 of the 32 outputs (wave-uniform -> s_load W)
// Computes g = relu(emb[n_map[sel?sel[node]:node]] @ W)  (ROW -> 32)
// then o0 = g @ P0 (and o1 = g @ P1 if TWO) via an LDS exchange of g.
template <int ROW, bool TWO>
__global__ __launch_bounds__(256) void nodek(
    const float* __restrict__ emb, const int* __restrict__ n_map,
    const int* __restrict__ sel, const float* __restrict__ W,
    const float* __restrict__ P0, const float* __restrict__ P1,
    float* __restrict__ o0, float* __restrict__ o1, int n) {
    __shared__ float g_lds[64 * 33];  // +1 pad per node row: conflict-free

    const int lane = threadIdx.x & 63;
    // wave-uniform by construction; readfirstlane forces SGPR -> s_load for W/P
    const int oct = __builtin_amdgcn_readfirstlane(threadIdx.x >> 6);

    const int node = blockIdx.x * 64 + lane;
    const bool valid = node < n;
    const int cn = valid ? node : n - 1;  // clamp: keep all lanes active
    const int local = sel ? sel[cn] : cn;
    const int gn = n_map[local];

    const float* row = emb + (size_t)gn * ROW;
    const float* Wo = W + oct * 8;  // my 8-column slice, wave-uniform rows

    float acc[8];
#pragma unroll
    for (int t = 0; t < 8; ++t) acc[t] = 0.f;

#pragma unroll 4
    for (int j0 = 0; j0 < ROW; j0 += 4) {
        float4 r4 = *(const float4*)(row + j0);  // per-lane gather, 16B
        const float* w0 = Wo + (size_t)(j0 + 0) * HID;
        const float* w1 = Wo + (size_t)(j0 + 1) * HID;
        const float* w2 = Wo + (size_t)(j0 + 2) * HID;
        const float* w3 = Wo + (size_t)(j0 + 3) * HID;
#pragma unroll
        for (int t = 0; t < 8; ++t) acc[t] = fmaf(r4.x, w0[t], acc[t]);
#pragma unroll
        for (int t = 0; t < 8; ++t) acc[t] = fmaf(r4.y, w1[t], acc[t]);
#pragma unroll
        for (int t = 0; t < 8; ++t) acc[t] = fmaf(r4.z, w2[t], acc[t]);
#pragma unroll
        for (int t = 0; t < 8; ++t) acc[t] = fmaf(r4.w, w3[t], acc[t]);
    }

    // relu -> LDS exchange (addr%32 = (lane+idx)%32 -> conflict-free)
#pragma unroll
    for (int t = 0; t < 8; ++t)
        g_lds[lane * 33 + oct * 8 + t] = fmaxf(acc[t], 0.f);
    __syncthreads();

    // projections: each thread emits 8 outputs per projection
    float p0[8], p1[8];
#pragma unroll
    for (int t = 0; t < 8; ++t) { p0[t] = 0.f; p1[t] = 0.f; }
    const float* P0o = P0 + oct * 8;
    const float* P1o = TWO ? (P1 + oct * 8) : P0o;
#pragma unroll 8
    for (int j = 0; j < HID; ++j) {
        float gv = g_lds[lane * 33 + j];  // scalar ds_read, conflict-free
        const float* pr0 = P0o + j * HID;
#pragma unroll
        for (int t = 0; t < 8; ++t) p0[t] = fmaf(gv, pr0[t], p0[t]);
        if (TWO) {
            const float* pr1 = P1o + j * HID;
#pragma unroll
            for (int t = 0; t < 8; ++t) p1[t] = fmaf(gv, pr1[t], p1[t]);
        }
    }

    if (valid) {
        float* d0 = o0 + (size_t)node * HID + oct * 8;
        float4 v0a = {p0[0], p0[1], p0[2], p0[3]};
        float4 v0b = {p0[4], p0[5], p0[6], p0[7]};
        *(float4*)(d0 + 0) = v0a;
        *(float4*)(d0 + 4) = v0b;
        if (TWO) {
            float* d1 = o1 + (size_t)node * HID + oct * 8;
            float4 v1a = {p1[0], p1[1], p1[2], p1[3]};
            float4 v1b = {p1[4], p1[5], p1[6], p1[7]};
            *(float4*)(d1 + 0) = v1a;
            *(float4*)(d1 + 4) = v1b;
        }
    }
}

// ---------------------------------------------------------------------------
// Per-edge: att = relu(SA[src] + DB[dst] + t2[batch] + be1) @ We2 + be2
// Writes att to its own slab and MIN_WEIGHT to the other slab (the two hop
// index sets partition [0,E), so together the two edge launches cover d_out).
__global__ __launch_bounds__(256) void edge_kernel(
    const int* __restrict__ hop_idx, int n_e, const int* __restrict__ src,
    const int* __restrict__ dst, const int* __restrict__ e_batch,
    const float* __restrict__ SA, const float* __restrict__ DB,
    const float* __restrict__ t2, const float* __restrict__ be1,
    const float* __restrict__ We2, const float* __restrict__ be2,
    float* __restrict__ out_att, float* __restrict__ out_min) {
    int i = blockIdx.x * blockDim.x + threadIdx.x;
    if (i >= n_e) return;
    int e = hop_idx[i];
    const float* sv = SA + (size_t)src[e] * HID;
    const float* dv = DB + (size_t)dst[e] * HID;
    const float* tv = t2 + (size_t)e_batch[e] * HID;
    float att = be2[0];
#pragma unroll
    for (int k = 0; k < HID; k += 4) {
        float4 s4 = *(const float4*)(sv + k);
        float4 d4 = *(const float4*)(dv + k);
        float4 t4 = *(const float4*)(tv + k);
        float h;
        h = fmaxf(s4.x + d4.x + t4.x + be1[k + 0], 0.f); att = fmaf(h, We2[k + 0], att);
        h = fmaxf(s4.y + d4.y + t4.y + be1[k + 1], 0.f); att = fmaf(h, We2[k + 1], att);
        h = fmaxf(s4.z + d4.z + t4.z + be1[k + 2], 0.f); att = fmaf(h, We2[k + 2], att);
        h = fmaxf(s4.w + d4.w + t4.w + be1[k + 3], 0.f); att = fmaf(h, We2[k + 3], att);
    }
    out_att[e] = att;
    out_min[e] = MIN_WEIGHT;
}

// ---------------------------------------------------------------------------
extern "C" void kernel_launch(void* const* d_in, const int* in_sizes, int n_in,
                              void* d_out, int out_size, void* d_ws, size_t ws_size,
                              hipStream_t stream) {
    const float* emb0 = (const float*)d_in[0];
    const float* emb1 = (const float*)d_in[1];
    const float* emb2 = (const float*)d_in[2];
    const int* n_map = (const int*)d_in[3];
    const int* src = (const int*)d_in[4];
    const int* dst = (const int*)d_in[5];
    const int* e_batch = (const int*)d_in[6];
    const int* offset_node = (const int*)d_in[7];
    const int* one_hop = (const int*)d_in[8];
    const int* two_hop = (const int*)d_in[9];
    const float* W0 = (const float*)d_in[10];
    const float* W1 = (const float*)d_in[11];
    const float* W2 = (const float*)d_in[12];
    const float* We1 = (const float*)d_in[13];
    const float* be1 = (const float*)d_in[14];
    const float* We2 = (const float*)d_in[15];
    const float* be2 = (const float*)d_in[16];

    const int n_nodes = in_sizes[3];
    const int E = in_sizes[4];
    const int batch = in_sizes[7];
    const int H1 = in_sizes[8];  // one-hop edge count
    const int H2 = in_sizes[9];  // two-hop edge count

    float* out = (float*)d_out;

    const float* A = We1;             // rows 0..31   (multiplies s)
    const float* B = We1 + 32 * HID;  // rows 32..63  (multiplies d)
    const float* T = We1 + 64 * HID;  // rows 64..95  (multiplies t)

    // workspace layout: a0 | a1 | b1 | b2 | t2
    float* a0 = (float*)d_ws;
    float* a1 = a0 + (size_t)n_nodes * HID;
    float* b1 = a1 + (size_t)n_nodes * HID;
    float* b2 = b1 + (size_t)n_nodes * HID;
    float* t2 = b2 + (size_t)n_nodes * HID;

    const int nblk = (n_nodes + 63) / 64;
    // a0 = relu(emb0@W0)@A
    nodek<128, false><<<nblk, 256, 0, stream>>>(
        emb0, n_map, nullptr, W0, A, nullptr, a0, nullptr, n_nodes);
    // a1 = relu(emb1@W1)@A ; b1 = relu(emb1@W1)@B
    nodek<256, true><<<nblk, 256, 0, stream>>>(
        emb1, n_map, nullptr, W1, A, B, a1, b1, n_nodes);
    // b2 = relu(emb2@W2)@B
    nodek<64, false><<<nblk, 256, 0, stream>>>(
        emb2, n_map, nullptr, W2, B, nullptr, b2, nullptr, n_nodes);
    // t2 = relu(emb2[n_map[offset_node]]@W2)@T
    nodek<64, false><<<(batch + 63) / 64, 256, 0, stream>>>(
        emb2, n_map, offset_node, W2, T, nullptr, t2, nullptr, batch);

    // one-hop edges: att -> slab 1, MIN -> slab 0 (src via W1@A, dst via W2@B)
    edge_kernel<<<(H1 + 255) / 256, 256, 0, stream>>>(
        one_hop, H1, src, dst, e_batch, a1, b2, t2, be1, We2, be2,
        out + (size_t)E, out);
    // two-hop edges: att -> slab 0, MIN -> slab 1 (src via W0@A, dst via W1@B)
    edge_kernel<<<(H2 + 255) / 256, 256, 0, stream>>>(
        two_hop, H2, src, dst, e_batch, a0, b1, t2, be1, We2, be2,
        out, out + (size_t)E);
}